// Round 3
// baseline (423.684 us; speedup 1.0000x reference)
//
#include <hip/hip_runtime.h>
#include <hip/hip_bf16.h>

// Problem constants: B=4, T_p=T_f=16, S=256, D=2048, H=16, hd=128, T=64 tokens.
// All inputs AND outputs are float32 (per reference dtypes).

// ---------------------------------------------------------------------------
// 1) tokens[b][0..31][d] = mean over S of v_p / v_f
// grid 256 blocks x 256 thr: block = (tensor, row=b*16+t, dchunk of 1024)
__global__ __launch_bounds__(256) void mean_tokens_kernel(
    const float* __restrict__ v_p, const float* __restrict__ v_f,
    float* __restrict__ tokens)
{
    int bid   = blockIdx.x;
    int which = bid >> 7;          // 0: v_p, 1: v_f
    int rem   = bid & 127;
    int row   = rem >> 1;          // 0..63 = b*16+t
    int dchunk= rem & 1;
    int b = row >> 4;
    int t = row & 15;
    int d = (dchunk << 10) + (threadIdx.x << 2);
    const float* src = (which ? v_f : v_p) + ((size_t)row << 19) + d; // row*256*2048
    float4 a0 = {0,0,0,0}, a1 = {0,0,0,0}, a2 = {0,0,0,0}, a3 = {0,0,0,0};
    for (int s = 0; s < 256; s += 4) {
        float4 x0 = *reinterpret_cast<const float4*>(src + (size_t)(s+0) * 2048);
        float4 x1 = *reinterpret_cast<const float4*>(src + (size_t)(s+1) * 2048);
        float4 x2 = *reinterpret_cast<const float4*>(src + (size_t)(s+2) * 2048);
        float4 x3 = *reinterpret_cast<const float4*>(src + (size_t)(s+3) * 2048);
        a0.x += x0.x; a0.y += x0.y; a0.z += x0.z; a0.w += x0.w;
        a1.x += x1.x; a1.y += x1.y; a1.z += x1.z; a1.w += x1.w;
        a2.x += x2.x; a2.y += x2.y; a2.z += x2.z; a2.w += x2.w;
        a3.x += x3.x; a3.y += x3.y; a3.z += x3.z; a3.w += x3.w;
    }
    const float inv = 1.f / 256.f;
    float4 o;
    o.x = (a0.x + a1.x + a2.x + a3.x) * inv;
    o.y = (a0.y + a1.y + a2.y + a3.y) * inv;
    o.z = (a0.z + a1.z + a2.z + a3.z) * inv;
    o.w = (a0.w + a1.w + a2.w + a3.w) * inv;
    int tok = (which << 4) + t;     // 0..31
    *reinterpret_cast<float4*>(&tokens[((size_t)(b * 64 + tok) << 11) + d]) = o;
}

// ---------------------------------------------------------------------------
// 2) tokens[b][32..63][d] = a_p / a_f  (copy).  grid 256 x 256 (65536 float4)
__global__ __launch_bounds__(256) void pack_audio_kernel(
    const float* __restrict__ a_p, const float* __restrict__ a_f,
    float* __restrict__ tokens)
{
    int i = blockIdx.x * 256 + threadIdx.x;  // float4 index
    int which = i >> 15;                     // 32768 float4 per tensor
    int j = i & 32767;
    const float* src = which ? a_f : a_p;
    float4 v = *reinterpret_cast<const float4*>(src + ((size_t)j << 2));
    int b  = j >> 13;                        // 8192 float4 per batch
    int r  = j & 8191;
    int t  = r >> 9;                         // 512 float4 per row
    int d4 = r & 511;
    int tok = 32 + (which << 4) + t;
    *reinterpret_cast<float4*>(&tokens[((size_t)(b * 64 + tok) << 11) + ((size_t)d4 << 2)]) = v;
}

// ---------------------------------------------------------------------------
// 3) f32 tiled GEMM: C[M,N] = A[M,K] @ B[K,N] (+bias). 64x64 tile, BK=16.
__global__ __launch_bounds__(256) void gemm_f32_kernel(
    const float* __restrict__ A, const float* __restrict__ B,
    const float* __restrict__ bias, float* __restrict__ C,
    int M, int N, int K)
{
    __shared__ float As[16][64];   // stored transposed: As[k][m]
    __shared__ float Bs[16][64];
    const int tid = threadIdx.x;
    const int bm = blockIdx.y * 64;
    const int bn = blockIdx.x * 64;
    const int ty = tid >> 4;            // 0..15 -> C rows ty*4..+3
    const int tx = tid & 15;            // 0..15 -> C cols tx*4..+3
    const int am = tid >> 2;            // 0..63
    const int ak = (tid & 3) << 2;      // 0,4,8,12
    const int bk = tid >> 4;            // 0..15
    const int bn4 = (tid & 15) << 2;
    float acc[4][4] = {{0.f,0.f,0.f,0.f},{0.f,0.f,0.f,0.f},{0.f,0.f,0.f,0.f},{0.f,0.f,0.f,0.f}};
    for (int k0 = 0; k0 < K; k0 += 16) {
        float4 av = *reinterpret_cast<const float4*>(A + (size_t)(bm + am) * K + k0 + ak);
        float4 bv = *reinterpret_cast<const float4*>(B + (size_t)(k0 + bk) * N + bn + bn4);
        __syncthreads();
        As[ak + 0][am] = av.x;
        As[ak + 1][am] = av.y;
        As[ak + 2][am] = av.z;
        As[ak + 3][am] = av.w;
        *reinterpret_cast<float4*>(&Bs[bk][bn4]) = bv;
        __syncthreads();
        #pragma unroll
        for (int kk = 0; kk < 16; ++kk) {
            float4 a4 = *reinterpret_cast<const float4*>(&As[kk][ty << 2]);
            float4 b4 = *reinterpret_cast<const float4*>(&Bs[kk][tx << 2]);
            float a[4] = {a4.x, a4.y, a4.z, a4.w};
            float bb[4] = {b4.x, b4.y, b4.z, b4.w};
            #pragma unroll
            for (int i = 0; i < 4; ++i)
                #pragma unroll
                for (int j = 0; j < 4; ++j)
                    acc[i][j] += a[i] * bb[j];
        }
    }
    #pragma unroll
    for (int i = 0; i < 4; ++i) {
        int row = bm + (ty << 2) + i;
        float4 o;
        float bs0 = bias ? bias[bn + (tx << 2) + 0] : 0.f;
        float bs1 = bias ? bias[bn + (tx << 2) + 1] : 0.f;
        float bs2 = bias ? bias[bn + (tx << 2) + 2] : 0.f;
        float bs3 = bias ? bias[bn + (tx << 2) + 3] : 0.f;
        o.x = acc[i][0] + bs0;
        o.y = acc[i][1] + bs1;
        o.z = acc[i][2] + bs2;
        o.w = acc[i][3] + bs3;
        *reinterpret_cast<float4*>(&C[(size_t)row * N + bn + (tx << 2)]) = o;
    }
}

// ---------------------------------------------------------------------------
// 4) RoPE in-place on q,k halves of qkv.  grid 256 rows x 256 thr.
__global__ __launch_bounds__(256) void rope_kernel(float* __restrict__ qkv)
{
    int row = blockIdx.x;      // b*64 + t
    int t = row & 63;
    float* q = qkv + (size_t)row * 6144;
    for (int i = threadIdx.x; i < 1024; i += 256) {
        int h = i >> 6;
        int d = i & 63;
        float invf = powf(10000.f, -(float)d * (1.f / 64.f));
        float ang = (float)t * invf;
        float c = cosf(ang), s = sinf(ang);
        int i0 = h * 128 + d;
        float q1 = q[i0], q2 = q[i0 + 64];
        q[i0]      = q1 * c - q2 * s;
        q[i0 + 64] = q2 * c + q1 * s;
        float* k = q + 2048;
        float k1 = k[i0], k2 = k[i0 + 64];
        k[i0]      = k1 * c - k2 * s;
        k[i0 + 64] = k2 * c + k1 * s;
    }
}

// ---------------------------------------------------------------------------
// 5) Attention: one block per (b,h). T=64, hd=128. Causal softmax.
// Thread (qi=tid>>2, g=tid&3): 16 score cols (ki=4j+g), then 32 out dims.
__global__ __launch_bounds__(256) void attn_kernel(
    const float* __restrict__ qkv, float* __restrict__ attn_out)
{
    __shared__ float q_s[64 * 128];   // 32KB; reused as p_s[64][65]
    __shared__ float k_s[64 * 128];   // 32KB; reused as v_s
    int b = blockIdx.x >> 4;
    int h = blockIdx.x & 15;
    int tid = threadIdx.x;
    const float* base = qkv + (size_t)(b * 64) * 6144 + h * 128;
    #pragma unroll
    for (int r = 0; r < 8; ++r) {
        int idx = tid + (r << 8);
        int t = idx >> 5;
        int d = (idx & 31) << 2;
        const float* src = base + (size_t)t * 6144 + d;
        *reinterpret_cast<float4*>(&q_s[t * 128 + d]) = *reinterpret_cast<const float4*>(src);
        *reinterpret_cast<float4*>(&k_s[t * 128 + d]) = *reinterpret_cast<const float4*>(src + 2048);
    }
    __syncthreads();
    int qi = tid >> 2;
    int g  = tid & 3;
    float pv[16];
    #pragma unroll
    for (int j = 0; j < 16; ++j) pv[j] = 0.f;
    for (int d = 0; d < 128; d += 4) {
        float4 a = *reinterpret_cast<const float4*>(&q_s[qi * 128 + d]);
        #pragma unroll
        for (int j = 0; j < 16; ++j) {
            int ki = (j << 2) + g;
            float4 bb = *reinterpret_cast<const float4*>(&k_s[ki * 128 + d]);
            pv[j] += a.x * bb.x + a.y * bb.y + a.z * bb.z + a.w * bb.w;
        }
    }
    const float scale = 0.0883883476483184405f;   // 128^-0.5
    float m = -1e30f;
    #pragma unroll
    for (int j = 0; j < 16; ++j) {
        int ki = (j << 2) + g;
        pv[j] = (ki <= qi) ? pv[j] * scale : -1e30f;
        m = fmaxf(m, pv[j]);
    }
    m = fmaxf(m, __shfl_xor(m, 1));
    m = fmaxf(m, __shfl_xor(m, 2));
    float l = 0.f;
    #pragma unroll
    for (int j = 0; j < 16; ++j) {
        float e = (pv[j] > -1e29f) ? expf(pv[j] - m) : 0.f;
        pv[j] = e;
        l += e;
    }
    l += __shfl_xor(l, 1);
    l += __shfl_xor(l, 2);
    float inv_l = 1.f / l;
    __syncthreads();                  // done reading q_s / k_s
    float* p_s = q_s;                 // [64][65] padded (bank-conflict-free)
    #pragma unroll
    for (int j = 0; j < 16; ++j) p_s[qi * 65 + (j << 2) + g] = pv[j] * inv_l;
    float* v_s = k_s;
    #pragma unroll
    for (int r = 0; r < 8; ++r) {
        int idx = tid + (r << 8);
        int t = idx >> 5;
        int d = (idx & 31) << 2;
        *reinterpret_cast<float4*>(&v_s[t * 128 + d]) =
            *reinterpret_cast<const float4*>(base + (size_t)t * 6144 + 4096 + d);
    }
    __syncthreads();
    int d0 = g << 5;
    float4 acc[8];
    #pragma unroll
    for (int u = 0; u < 8; ++u) acc[u] = {0.f, 0.f, 0.f, 0.f};
    for (int ki = 0; ki < 64; ++ki) {
        float p = p_s[qi * 65 + ki];
        #pragma unroll
        for (int u = 0; u < 8; ++u) {
            float4 vv = *reinterpret_cast<const float4*>(&v_s[ki * 128 + d0 + (u << 2)]);
            acc[u].x += p * vv.x;
            acc[u].y += p * vv.y;
            acc[u].z += p * vv.z;
            acc[u].w += p * vv.w;
        }
    }
    float* orow = attn_out + (size_t)(b * 64 + qi) * 2048 + h * 128 + d0;
    #pragma unroll
    for (int u = 0; u < 8; ++u)
        *reinterpret_cast<float4*>(&orow[u << 2]) = acc[u];
}

// ---------------------------------------------------------------------------
// 6) Broadcast video outputs: out rows -> S=256 copies, f32 stores.
// grid 2048 = 2 tensors x 64 rows x 16 s-chunks; thread owns 8 d's (2 float4).
__global__ __launch_bounds__(256) void bcast_video_kernel(
    const float* __restrict__ outp, float* __restrict__ d_out)
{
    int bid = blockIdx.x;
    int which = bid >> 10;          // 0: v_p_out, 1: v_f_out
    int rem = bid & 1023;
    int row = rem >> 4;             // b*16 + t
    int schunk = rem & 15;
    int b = row >> 4;
    int t = row & 15;
    const float* src = outp + (size_t)(b * 64 + (which << 4) + t) * 2048 + threadIdx.x * 8;
    float4 o0 = *reinterpret_cast<const float4*>(src);
    float4 o1 = *reinterpret_cast<const float4*>(src + 4);
    size_t base = (size_t)which * 33554432 +
                  ((size_t)row * 256 + (size_t)schunk * 16) * 2048 + threadIdx.x * 8;
    float* dst = d_out + base;
    #pragma unroll
    for (int s = 0; s < 16; ++s) {
        *reinterpret_cast<float4*>(dst + (size_t)s * 2048)     = o0;
        *reinterpret_cast<float4*>(dst + (size_t)s * 2048 + 4) = o1;
    }
}

// ---------------------------------------------------------------------------
// 7) Audio outputs: out rows 32..63 -> a_p_out, a_f_out (f32). grid 256 x 256.
__global__ __launch_bounds__(256) void audio_out_kernel(
    const float* __restrict__ outp, float* __restrict__ d_out)
{
    int i = blockIdx.x * 256 + threadIdx.x;  // float4 group, 0..65535
    int which = i >> 15;                     // 32768 float4 per tensor
    int j = i & 32767;
    int b = j >> 13;                         // 8192 float4 per batch
    int r = j & 8191;
    int t = r >> 9;                          // 512 float4 per row
    int gq = r & 511;
    const float* src = outp + (size_t)(b * 64 + 32 + (which << 4) + t) * 2048 + gq * 4;
    float4 v = *reinterpret_cast<const float4*>(src);
    float* dst = d_out + 67108864 + (size_t)which * 131072 +
                 (size_t)(b * 16 + t) * 2048 + gq * 4;
    *reinterpret_cast<float4*>(dst) = v;
}

// ---------------------------------------------------------------------------
extern "C" void kernel_launch(void* const* d_in, const int* in_sizes, int n_in,
                              void* d_out, int out_size, void* d_ws, size_t ws_size,
                              hipStream_t stream)
{
    const float* v_p    = (const float*)d_in[0];
    const float* v_f    = (const float*)d_in[1];
    const float* a_p    = (const float*)d_in[2];
    const float* a_f    = (const float*)d_in[3];
    const float* W_qkv  = (const float*)d_in[4];
    const float* W_proj = (const float*)d_in[5];
    const float* b_proj = (const float*)d_in[6];
    float* out_f = (float*)d_out;

    char* ws = (char*)d_ws;
    float* tokens = (float*)(ws);                                  // 256*2048 f32 (2MB)
    float* qkv    = (float*)(ws + 2097152);                        // 256*6144 f32 (6MB)
    float* attn_o = (float*)(ws + 2097152 + 6291456);              // 256*2048 f32 (2MB)
    float* outp   = (float*)(ws + 2097152 + 6291456 + 2097152);    // 256*2048 f32 (2MB)

    mean_tokens_kernel<<<256, 256, 0, stream>>>(v_p, v_f, tokens);
    pack_audio_kernel<<<256, 256, 0, stream>>>(a_p, a_f, tokens);
    gemm_f32_kernel<<<dim3(96, 4), 256, 0, stream>>>(tokens, W_qkv, nullptr, qkv, 256, 6144, 2048);
    rope_kernel<<<256, 256, 0, stream>>>(qkv);
    attn_kernel<<<64, 256, 0, stream>>>(qkv, attn_o);
    gemm_f32_kernel<<<dim3(32, 4), 256, 0, stream>>>(attn_o, W_proj, b_proj, outp, 256, 2048, 2048);
    bcast_video_kernel<<<2048, 256, 0, stream>>>(outp, out_f);
    audio_out_kernel<<<256, 256, 0, stream>>>(outp, out_f);
}

// Round 4
// 245.772 us; speedup vs baseline: 1.7239x; 1.7239x over previous
//
#include <hip/hip_runtime.h>
#include <hip/hip_bf16.h>
#include <stdint.h>

// Problem: B=4, T_p=T_f=16, S=256, D=2048, H=16, hd=128, T=64 tokens.
// Inputs f32; outputs f32. GEMMs run in bf16 MFMA (f32 accumulate).

using bf16x8v = __attribute__((ext_vector_type(8))) __bf16;
using f32x4v  = __attribute__((ext_vector_type(4))) float;

union Pack8 { __bf16 h[8]; uint4 u; };

// XOR-swizzled element offset inside a [64 rows][64 bf16] LDS tile:
// row stride 64 el (128B), 8 chunks of 8 el; chunk c lives at c^(row&7).
__device__ __forceinline__ int swz(int r, int c) {
    return (r << 6) + (((c ^ (r & 7))) << 3);
}

// ---------------------------------------------------------------------------
// 0) Transpose + convert weights: src f32 [2048][N] -> dst bf16 [N][2048].
// One block per 64x64 tile. grid = (2048/64) * (N/64).
__global__ __launch_bounds__(256) void prep_w_kernel(
    const float* __restrict__ src, __bf16* __restrict__ dst, int N)
{
    __shared__ float Ls[64][68];
    int tiles_n = N >> 6;
    int tn = blockIdx.x % tiles_n;
    int tk = blockIdx.x / tiles_n;
    int t = threadIdx.x;
    // read phase: 64x64 f32 tile, coalesced float4
    int rb = t >> 4;            // 0..15
    int c4 = (t & 15) << 2;     // 0..60
    #pragma unroll
    for (int s = 0; s < 4; ++s) {
        int r = rb + (s << 4);
        float4 v = *reinterpret_cast<const float4*>(
            src + (size_t)(tk * 64 + r) * N + tn * 64 + c4);
        *reinterpret_cast<float4*>(&Ls[r][c4]) = v;
    }
    __syncthreads();
    // write phase: out row c (n-index), 16 k-elements per thread
    int c  = t >> 2;            // 0..63
    int r0 = (t & 3) << 4;      // 0,16,32,48
    Pack8 p0, p1;
    #pragma unroll
    for (int i = 0; i < 8; ++i) p0.h[i] = (__bf16)Ls[r0 + i][c];
    #pragma unroll
    for (int i = 0; i < 8; ++i) p1.h[i] = (__bf16)Ls[r0 + 8 + i][c];
    __bf16* drow = dst + (size_t)(tn * 64 + c) * 2048 + tk * 64 + r0;
    *reinterpret_cast<uint4*>(drow)     = p0.u;
    *reinterpret_cast<uint4*>(drow + 8) = p1.u;
}

// ---------------------------------------------------------------------------
// 1a) mean stage 1: partial sums over s-chunks of 64. grid 1024 x 256.
__global__ __launch_bounds__(256) void mean_stage1_kernel(
    const float* __restrict__ v_p, const float* __restrict__ v_f,
    float* __restrict__ partials)
{
    int bid = blockIdx.x;
    int which  = bid >> 9;          // 0: v_p, 1: v_f
    int rem    = bid & 511;
    int row    = rem >> 3;          // 0..63 = b*16+t
    int dchunk = (rem >> 2) & 1;
    int schunk = rem & 3;
    int d = (dchunk << 10) + (threadIdx.x << 2);
    const float* src = (which ? v_f : v_p) + ((size_t)row << 19)
                     + ((size_t)(schunk << 6) << 11) + d;
    float4 a = {0.f, 0.f, 0.f, 0.f};
    #pragma unroll 8
    for (int s = 0; s < 64; ++s) {
        float4 x = *reinterpret_cast<const float4*>(src + ((size_t)s << 11));
        a.x += x.x; a.y += x.y; a.z += x.z; a.w += x.w;
    }
    int pr = which * 64 + row;
    *reinterpret_cast<float4*>(&partials[(size_t)((pr << 2) + schunk) * 2048 + d]) = a;
}

// 1b) mean stage 2: reduce 4 partials -> tokens_bf rows 0..31 (per batch).
// grid 128 x 256; thread handles 8 consecutive elements.
__global__ __launch_bounds__(256) void mean_stage2_kernel(
    const float* __restrict__ partials, __bf16* __restrict__ tokens_bf)
{
    int idx = (blockIdx.x * 256 + threadIdx.x) * 8;   // 0..262143
    int r = idx >> 11;            // 0..127 = which*64 + b*16+tt
    int d = idx & 2047;
    float s[8];
    #pragma unroll
    for (int i = 0; i < 8; ++i) s[i] = 0.f;
    #pragma unroll
    for (int sc = 0; sc < 4; ++sc) {
        const float* p = partials + (size_t)((r << 2) + sc) * 2048 + d;
        float4 x0 = *reinterpret_cast<const float4*>(p);
        float4 x1 = *reinterpret_cast<const float4*>(p + 4);
        s[0] += x0.x; s[1] += x0.y; s[2] += x0.z; s[3] += x0.w;
        s[4] += x1.x; s[5] += x1.y; s[6] += x1.z; s[7] += x1.w;
    }
    const float inv = 1.f / 256.f;
    int which = r >> 6, rr = r & 63;
    int b = rr >> 4, tt = rr & 15;
    int tokrow = b * 64 + which * 16 + tt;
    Pack8 p;
    #pragma unroll
    for (int i = 0; i < 8; ++i) p.h[i] = (__bf16)(s[i] * inv);
    *reinterpret_cast<uint4*>(&tokens_bf[(size_t)tokrow * 2048 + d]) = p.u;
}

// 1c) audio pack -> tokens_bf rows 32..63 per batch. grid 128 x 256.
__global__ __launch_bounds__(256) void pack_audio_kernel(
    const float* __restrict__ a_p, const float* __restrict__ a_f,
    __bf16* __restrict__ tokens_bf)
{
    int g = blockIdx.x * 256 + threadIdx.x;   // 8-elem group, 0..32767
    int which = g >> 14;
    int j = g & 16383;
    int b = j >> 12;
    int rr = j & 4095;
    int tt = rr >> 8;
    int gq = rr & 255;
    const float* src = (which ? a_f : a_p) + (size_t)(b * 16 + tt) * 2048 + gq * 8;
    float4 x0 = *reinterpret_cast<const float4*>(src);
    float4 x1 = *reinterpret_cast<const float4*>(src + 4);
    Pack8 p;
    p.h[0] = (__bf16)x0.x; p.h[1] = (__bf16)x0.y; p.h[2] = (__bf16)x0.z; p.h[3] = (__bf16)x0.w;
    p.h[4] = (__bf16)x1.x; p.h[5] = (__bf16)x1.y; p.h[6] = (__bf16)x1.z; p.h[7] = (__bf16)x1.w;
    int tokrow = b * 64 + 32 + which * 16 + tt;
    *reinterpret_cast<uint4*>(&tokens_bf[(size_t)tokrow * 2048 + gq * 8]) = p.u;
}

// ---------------------------------------------------------------------------
// 2) bf16 MFMA GEMM: C[M=grid.y*64][N] = A[M][2048]bf16 * Bt[N][2048]bf16 (+bias)
// 64x64 tile, BK=64, 4 waves; wave w computes rows 16w..16w+15 x 64 cols.
__global__ __launch_bounds__(256) void gemm_bf16_kernel(
    const __bf16* __restrict__ A, const __bf16* __restrict__ Bt,
    const float* __restrict__ bias, float* __restrict__ C, int N)
{
    __shared__ __bf16 As[4096];
    __shared__ __bf16 Bs[4096];
    const int t = threadIdx.x;
    const int m0 = blockIdx.y << 6;
    const int n0 = blockIdx.x << 6;
    const int lane = t & 63;
    const int wm = (t >> 6) << 4;        // wave's m offset (0,16,32,48)
    const int lrow = lane & 15;
    const int lk = lane >> 4;            // 0..3
    // staging assignment: rounds r2 in {0,1}: row=(t>>3)+32*r2, chunk c=t&7
    const int srow = t >> 3;             // 0..31
    const int sc = t & 7;
    const __bf16* gA = A  + (size_t)(m0 + srow) * 2048 + (sc << 3);
    const __bf16* gB = Bt + (size_t)(n0 + srow) * 2048 + (sc << 3);
    const int wA0 = swz(srow, sc), wA1 = swz(srow + 32, sc);

    f32x4v acc[4] = {{0.f,0.f,0.f,0.f},{0.f,0.f,0.f,0.f},
                     {0.f,0.f,0.f,0.f},{0.f,0.f,0.f,0.f}};
    uint4 pa0, pa1, pb0, pb1;
    // prefetch k-tile 0
    pa0 = *reinterpret_cast<const uint4*>(gA);
    pa1 = *reinterpret_cast<const uint4*>(gA + 32 * 2048);
    pb0 = *reinterpret_cast<const uint4*>(gB);
    pb1 = *reinterpret_cast<const uint4*>(gB + 32 * 2048);

    for (int kt = 0; kt < 32; ++kt) {
        __syncthreads();
        *reinterpret_cast<uint4*>(&As[wA0]) = pa0;
        *reinterpret_cast<uint4*>(&As[wA1]) = pa1;
        *reinterpret_cast<uint4*>(&Bs[wA0]) = pb0;
        *reinterpret_cast<uint4*>(&Bs[wA1]) = pb1;
        __syncthreads();
        if (kt < 31) {
            const __bf16* nA = gA + (kt + 1) * 64;
            const __bf16* nB = gB + (kt + 1) * 64;
            pa0 = *reinterpret_cast<const uint4*>(nA);
            pa1 = *reinterpret_cast<const uint4*>(nA + 32 * 2048);
            pb0 = *reinterpret_cast<const uint4*>(nB);
            pb1 = *reinterpret_cast<const uint4*>(nB + 32 * 2048);
        }
        #pragma unroll
        for (int s = 0; s < 2; ++s) {
            int cA = (s << 2) + lk;
            bf16x8v af = *reinterpret_cast<const bf16x8v*>(&As[swz(wm + lrow, cA)]);
            #pragma unroll
            for (int j = 0; j < 4; ++j) {
                bf16x8v bf = *reinterpret_cast<const bf16x8v*>(&Bs[swz((j << 4) + lrow, cA)]);
                acc[j] = __builtin_amdgcn_mfma_f32_16x16x32_bf16(af, bf, acc[j], 0, 0, 0);
            }
        }
    }
    // epilogue: C/D layout col=lane&15, row=(lane>>4)*4+reg
    #pragma unroll
    for (int j = 0; j < 4; ++j) {
        int col = n0 + (j << 4) + lrow;
        float bv = bias ? bias[col] : 0.f;
        #pragma unroll
        for (int e = 0; e < 4; ++e) {
            int row = m0 + wm + (lk << 2) + e;
            C[(size_t)row * N + col] = acc[j][e] + bv;
        }
    }
}

// ---------------------------------------------------------------------------
// 3) RoPE in-place on q,k halves of qkv (f32). grid 256 x 256.
__global__ __launch_bounds__(256) void rope_kernel(float* __restrict__ qkv)
{
    int row = blockIdx.x;      // b*64 + t
    int t = row & 63;
    float* q = qkv + (size_t)row * 6144;
    for (int i = threadIdx.x; i < 1024; i += 256) {
        int h = i >> 6;
        int d = i & 63;
        float invf = powf(10000.f, -(float)d * (1.f / 64.f));
        float ang = (float)t * invf;
        float c = cosf(ang), s = sinf(ang);
        int i0 = h * 128 + d;
        float q1 = q[i0], q2 = q[i0 + 64];
        q[i0]      = q1 * c - q2 * s;
        q[i0 + 64] = q2 * c + q1 * s;
        float* k = q + 2048;
        float k1 = k[i0], k2 = k[i0 + 64];
        k[i0]      = k1 * c - k2 * s;
        k[i0 + 64] = k2 * c + k1 * s;
    }
}

// ---------------------------------------------------------------------------
// 4) Attention per (b,h); causal softmax; output bf16 (feeds proj GEMM).
__global__ __launch_bounds__(256) void attn_kernel(
    const float* __restrict__ qkv, __bf16* __restrict__ attn_out)
{
    __shared__ float q_s[64 * 128];   // reused as p_s[64][65]
    __shared__ float k_s[64 * 128];   // reused as v_s
    int b = blockIdx.x >> 4;
    int h = blockIdx.x & 15;
    int tid = threadIdx.x;
    const float* base = qkv + (size_t)(b * 64) * 6144 + h * 128;
    #pragma unroll
    for (int r = 0; r < 8; ++r) {
        int idx = tid + (r << 8);
        int t = idx >> 5;
        int d = (idx & 31) << 2;
        const float* src = base + (size_t)t * 6144 + d;
        *reinterpret_cast<float4*>(&q_s[t * 128 + d]) = *reinterpret_cast<const float4*>(src);
        *reinterpret_cast<float4*>(&k_s[t * 128 + d]) = *reinterpret_cast<const float4*>(src + 2048);
    }
    __syncthreads();
    int qi = tid >> 2;
    int g  = tid & 3;
    float pv[16];
    #pragma unroll
    for (int j = 0; j < 16; ++j) pv[j] = 0.f;
    for (int d = 0; d < 128; d += 4) {
        float4 a = *reinterpret_cast<const float4*>(&q_s[qi * 128 + d]);
        #pragma unroll
        for (int j = 0; j < 16; ++j) {
            int ki = (j << 2) + g;
            float4 bb = *reinterpret_cast<const float4*>(&k_s[ki * 128 + d]);
            pv[j] += a.x * bb.x + a.y * bb.y + a.z * bb.z + a.w * bb.w;
        }
    }
    const float scale = 0.0883883476483184405f;   // 128^-0.5
    float m = -1e30f;
    #pragma unroll
    for (int j = 0; j < 16; ++j) {
        int ki = (j << 2) + g;
        pv[j] = (ki <= qi) ? pv[j] * scale : -1e30f;
        m = fmaxf(m, pv[j]);
    }
    m = fmaxf(m, __shfl_xor(m, 1));
    m = fmaxf(m, __shfl_xor(m, 2));
    float l = 0.f;
    #pragma unroll
    for (int j = 0; j < 16; ++j) {
        float e = (pv[j] > -1e29f) ? expf(pv[j] - m) : 0.f;
        pv[j] = e;
        l += e;
    }
    l += __shfl_xor(l, 1);
    l += __shfl_xor(l, 2);
    float inv_l = 1.f / l;
    __syncthreads();
    float* p_s = q_s;
    #pragma unroll
    for (int j = 0; j < 16; ++j) p_s[qi * 65 + (j << 2) + g] = pv[j] * inv_l;
    float* v_s = k_s;
    #pragma unroll
    for (int r = 0; r < 8; ++r) {
        int idx = tid + (r << 8);
        int t = idx >> 5;
        int d = (idx & 31) << 2;
        *reinterpret_cast<float4*>(&v_s[t * 128 + d]) =
            *reinterpret_cast<const float4*>(base + (size_t)t * 6144 + 4096 + d);
    }
    __syncthreads();
    int d0 = g << 5;
    float4 acc[8];
    #pragma unroll
    for (int u = 0; u < 8; ++u) acc[u] = {0.f, 0.f, 0.f, 0.f};
    for (int ki = 0; ki < 64; ++ki) {
        float p = p_s[qi * 65 + ki];
        #pragma unroll
        for (int u = 0; u < 8; ++u) {
            float4 vv = *reinterpret_cast<const float4*>(&v_s[ki * 128 + d0 + (u << 2)]);
            acc[u].x += p * vv.x;
            acc[u].y += p * vv.y;
            acc[u].z += p * vv.z;
            acc[u].w += p * vv.w;
        }
    }
    __bf16* orow = attn_out + (size_t)(b * 64 + qi) * 2048 + h * 128 + d0;
    #pragma unroll
    for (int v = 0; v < 4; ++v) {
        Pack8 p;
        float4 a0 = acc[2 * v], a1 = acc[2 * v + 1];
        p.h[0] = (__bf16)a0.x; p.h[1] = (__bf16)a0.y; p.h[2] = (__bf16)a0.z; p.h[3] = (__bf16)a0.w;
        p.h[4] = (__bf16)a1.x; p.h[5] = (__bf16)a1.y; p.h[6] = (__bf16)a1.z; p.h[7] = (__bf16)a1.w;
        *reinterpret_cast<uint4*>(orow + v * 8) = p.u;
    }
}

// ---------------------------------------------------------------------------
// 5) Broadcast video outputs (f32). grid 2048 x 256.
__global__ __launch_bounds__(256) void bcast_video_kernel(
    const float* __restrict__ outp, float* __restrict__ d_out)
{
    int bid = blockIdx.x;
    int which = bid >> 10;
    int rem = bid & 1023;
    int row = rem >> 4;             // b*16 + t
    int schunk = rem & 15;
    int b = row >> 4;
    int t = row & 15;
    const float* src = outp + (size_t)(b * 64 + (which << 4) + t) * 2048 + threadIdx.x * 8;
    float4 o0 = *reinterpret_cast<const float4*>(src);
    float4 o1 = *reinterpret_cast<const float4*>(src + 4);
    size_t base = (size_t)which * 33554432 +
                  ((size_t)row * 256 + (size_t)schunk * 16) * 2048 + threadIdx.x * 8;
    float* dst = d_out + base;
    #pragma unroll
    for (int s = 0; s < 16; ++s) {
        *reinterpret_cast<float4*>(dst + (size_t)s * 2048)     = o0;
        *reinterpret_cast<float4*>(dst + (size_t)s * 2048 + 4) = o1;
    }
}

// ---------------------------------------------------------------------------
// 6) Audio outputs (f32). grid 256 x 256.
__global__ __launch_bounds__(256) void audio_out_kernel(
    const float* __restrict__ outp, float* __restrict__ d_out)
{
    int i = blockIdx.x * 256 + threadIdx.x;  // float4 group
    int which = i >> 15;
    int j = i & 32767;
    int b = j >> 13;
    int r = j & 8191;
    int t = r >> 9;
    int gq = r & 511;
    const float* src = outp + (size_t)(b * 64 + 32 + (which << 4) + t) * 2048 + gq * 4;
    float4 v = *reinterpret_cast<const float4*>(src);
    float* dst = d_out + 67108864 + (size_t)which * 131072 +
                 (size_t)(b * 16 + t) * 2048 + gq * 4;
    *reinterpret_cast<float4*>(dst) = v;
}

// ---------------------------------------------------------------------------
extern "C" void kernel_launch(void* const* d_in, const int* in_sizes, int n_in,
                              void* d_out, int out_size, void* d_ws, size_t ws_size,
                              hipStream_t stream)
{
    const float* v_p    = (const float*)d_in[0];
    const float* v_f    = (const float*)d_in[1];
    const float* a_p    = (const float*)d_in[2];
    const float* a_f    = (const float*)d_in[3];
    const float* W_qkv  = (const float*)d_in[4];
    const float* W_proj = (const float*)d_in[5];
    const float* b_proj = (const float*)d_in[6];
    float* out_f = (float*)d_out;

    char* ws = (char*)d_ws;
    __bf16* tokens_bf = (__bf16*)(ws);                       // 1 MB
    __bf16* Wt_qkv    = (__bf16*)(ws + 1048576);             // 25.17 MB
    __bf16* Wt_proj   = (__bf16*)(ws + 26214400);            // 8.39 MB
    float*  qkv       = (float*)(ws + 34603008);             // 6 MB
    __bf16* attn_bf   = (__bf16*)(ws + 40894464);            // 1 MB
    float*  outp      = (float*)(ws + 41943040);             // 2 MB
    float*  partials  = (float*)(ws + 44040192);             // 4 MB

    prep_w_kernel<<<3072, 256, 0, stream>>>(W_qkv, Wt_qkv, 6144);
    prep_w_kernel<<<1024, 256, 0, stream>>>(W_proj, Wt_proj, 2048);
    mean_stage1_kernel<<<1024, 256, 0, stream>>>(v_p, v_f, partials);
    mean_stage2_kernel<<<128, 256, 0, stream>>>(partials, tokens_bf);
    pack_audio_kernel<<<128, 256, 0, stream>>>(a_p, a_f, tokens_bf);
    gemm_bf16_kernel<<<dim3(96, 4), 256, 0, stream>>>(tokens_bf, Wt_qkv, nullptr, qkv, 6144);
    rope_kernel<<<256, 256, 0, stream>>>(qkv);
    attn_kernel<<<64, 256, 0, stream>>>(qkv, attn_bf);
    gemm_bf16_kernel<<<dim3(32, 4), 256, 0, stream>>>(attn_bf, Wt_proj, b_proj, outp, 2048);
    bcast_video_kernel<<<2048, 256, 0, stream>>>(outp, out_f);
    audio_out_kernel<<<256, 256, 0, stream>>>(outp, out_f);
}